// Round 5
// baseline (257.510 us; speedup 1.0000x reference)
//
#include <hip/hip_runtime.h>
#include <math.h>

#define W 1024
#define H 768
#define PIX (W*H)          // 786432
#define NIMG 4
#define SNUM 131072
#define BPI 3072           // preprocessing blocks per image, 256 pixels each
#define NB (NIMG*BPI)      // 12288
#define GRID_L 2048        // loss blocks (1D, XCD-swizzled)
#define MASKV (-1e-8f)

__device__ __forceinline__ void sobel_g(const float* __restrict__ img, int y, int x,
                                        float& gx, float& gy) {
    const float* r0 = img + (y - 1) * W + x;
    const float* r1 = r0 + W;
    const float* r2 = r1 + W;
    float a00 = r0[-1], a01 = r0[0], a02 = r0[1];
    float a10 = r1[-1],              a12 = r1[1];
    float a20 = r2[-1], a21 = r2[0], a22 = r2[1];
    gx = (a02 - a00) + 2.f * (a12 - a10) + (a22 - a20);
    gy = (a00 - a20) + 2.f * (a01 - a21) + (a02 - a22);
}

// ---- K0: Sobel magnitude + block max + pack {inp,tgt} + valid bits/counts ----
__global__ void sobel_pack_kernel(const float* __restrict__ inputs,
                                  const float* __restrict__ targets,
                                  const float* __restrict__ images,
                                  float2* __restrict__ pairIT,
                                  unsigned long long* __restrict__ vBits,
                                  float* __restrict__ blockmax,
                                  int* __restrict__ blkV,
                                  unsigned* __restrict__ counter) {
    int b = blockIdx.x, t = threadIdx.x;
    if (b == 0 && t == 0) *counter = 0;            // reset ticket for merged finalizer
    int i = b / BPI, bLoc = b - i * BPI;
    int gp = bLoc * 256 + t;
    int y = gp >> 10, x = gp & (W - 1);
    const float* img = images + (size_t)i * 3 * PIX;   // channel 0
    float e = 0.f;
    if (y >= 1 && y <= H - 2 && x >= 1 && x <= W - 2) {
        float gx, gy;
        sobel_g(img, y, x, gx, gy);
        e = sqrtf(gx * gx + gy * gy);
    }
    size_t off = (size_t)i * PIX + gp;
    float inv = inputs[off], tgv = targets[off];
    pairIT[off] = make_float2(inv, tgv);
    unsigned long long m = __ballot(tgv > MASKV);
    __shared__ float sm[256];
    __shared__ int sc[4];
    if ((t & 63) == 0) { vBits[off >> 6] = m; sc[t >> 6] = __popcll(m); }
    sm[t] = e;
    __syncthreads();
    for (int o = 128; o > 0; o >>= 1) {
        if (t < o) sm[t] = fmaxf(sm[t], sm[t + o]);
        __syncthreads();
    }
    if (t == 0) { blockmax[b] = sm[0]; blkV[b] = sc[0] + sc[1] + sc[2] + sc[3]; }
}

// ---- K1: per-image emax->thr + exclusive scan of blkV (3072 entries) ----
__global__ void emax_scanv_kernel(const float* __restrict__ blockmax,
                                  int* __restrict__ blkV,
                                  float* __restrict__ thrArr, int* __restrict__ vtot) {
    int i = blockIdx.x, t = threadIdx.x;   // 1024 threads
    __shared__ float sf[1024];
    __shared__ int si[1024];
    const float* bm = blockmax + i * BPI;
    sf[t] = fmaxf(fmaxf(bm[t], bm[t + 1024]), bm[t + 2048]);
    int* bv = blkV + i * BPI;
    int e0 = bv[3 * t], e1 = bv[3 * t + 1], e2 = bv[3 * t + 2];
    int s = e0 + e1 + e2;
    si[t] = s;
    __syncthreads();
    for (int o = 512; o > 0; o >>= 1) {
        if (t < o) sf[t] = fmaxf(sf[t], sf[t + o]);
        __syncthreads();
    }
    for (int o = 1; o < 1024; o <<= 1) {
        int v = (t >= o) ? si[t - o] : 0;
        __syncthreads();
        si[t] += v;
        __syncthreads();
    }
    int base = si[t] - s;
    bv[3 * t] = base; bv[3 * t + 1] = base + e0; bv[3 * t + 2] = base + e0 + e1;
    if (t == 0) thrArr[i] = 0.1f * sf[0];
    if (t == 1023) vtot[i] = si[1023];
}

// ---- K2: edge bits + per-block edge counts (Sobel recomputed) ----
__global__ void ebits_kernel(const float* __restrict__ images,
                             const float* __restrict__ thrArr,
                             unsigned long long* __restrict__ eBits,
                             int* __restrict__ blkE) {
    int b = blockIdx.x, t = threadIdx.x;
    int i = b / BPI, bLoc = b - i * BPI;
    int gp = bLoc * 256 + t;
    int y = gp >> 10, x = gp & (W - 1);
    const float* img = images + (size_t)i * 3 * PIX;
    float e = 0.f;
    if (y >= 1 && y <= H - 2 && x >= 1 && x <= W - 2) {
        float gx, gy;
        sobel_g(img, y, x, gx, gy);
        e = sqrtf(gx * gx + gy * gy);
    }
    float thr = thrArr[i];
    unsigned long long m = __ballot(e >= thr);
    __shared__ int sc[4];
    if ((t & 63) == 0) { eBits[((size_t)i * PIX + gp) >> 6] = m; sc[t >> 6] = __popcll(m); }
    __syncthreads();
    if (t == 0) blkE[b] = sc[0] + sc[1] + sc[2] + sc[3];
}

// ---- K3: exclusive scan of blkE ----
__global__ void scane_kernel(int* __restrict__ blkE, int* __restrict__ etot) {
    int i = blockIdx.x, t = threadIdx.x;
    __shared__ int si[1024];
    int* be = blkE + i * BPI;
    int e0 = be[3 * t], e1 = be[3 * t + 1], e2 = be[3 * t + 2];
    int s = e0 + e1 + e2;
    si[t] = s;
    __syncthreads();
    for (int o = 1; o < 1024; o <<= 1) {
        int v = (t >= o) ? si[t - o] : 0;
        __syncthreads();
        si[t] += v;
        __syncthreads();
    }
    int base = si[t] - s;
    be[3 * t] = base; be[3 * t + 1] = base + e0; be[3 * t + 2] = base + e0 + e1;
    if (t == 1023) etot[i] = si[1023];
}

// ---- K4: scatter {pixel,theta} for edge pixels; compV only if not all-valid ----
__global__ void scatter_kernel(const float* __restrict__ images,
                               const unsigned long long* __restrict__ eBits,
                               const unsigned long long* __restrict__ vBits,
                               const int* __restrict__ blkE, const int* __restrict__ blkV,
                               const int* __restrict__ vtot,
                               float2* __restrict__ anchorC, int* __restrict__ compV) {
    int b = blockIdx.x, t = threadIdx.x;
    int i = b / BPI, bLoc = b - i * BPI;
    int gp = bLoc * 256 + t;
    int lane = t & 63, w = t >> 6;
    size_t woff = ((size_t)i * PIX + bLoc * 256) >> 6;
    unsigned long long em = eBits[woff + w], vm = vBits[woff + w];
    __shared__ int sWE[4], sWV[4];
    if (lane == 0) { sWE[w] = __popcll(em); sWV[w] = __popcll(vm); }
    __syncthreads();
    int preE = 0, preV = 0;
    for (int k = 0; k < w; k++) { preE += sWE[k]; preV += sWV[k]; }
    unsigned long long lm = (1ull << lane) - 1ull;
    int erank = blkE[b] + preE + __popcll(em & lm);
    int vrank = blkV[b] + preV + __popcll(vm & lm);
    if ((em >> lane) & 1) {
        int y = gp >> 10, x = gp & (W - 1);
        float th = 0.f;
        if (y >= 1 && y <= H - 2 && x >= 1 && x <= W - 2) {
            float gx, gy;
            const float* img = images + (size_t)i * 3 * PIX;
            sobel_g(img, y, x, gx, gy);
            th = atan2f(gy, gx);
        }
        anchorC[(size_t)i * PIX + erank] = make_float2(__int_as_float(gp), th);
    }
    if (((vm >> lane) & 1) && vtot[i] < PIX) compV[(size_t)i * PIX + vrank] = gp;
}

// ---- loss (XCD-swizzled) + merged final reduce ----
__device__ __forceinline__ void pair_term(float2 a, float2 b, float& eqs, float& uns) {
    float cm = ((a.y > MASKV) ? 1.f : 0.f) * ((b.y > MASKV) ? 1.f : 0.f);
    float ratio = (a.y + 1e-6f) / (b.y + 1e-6f);
    const float HIv = 1.03f;
    const float LOv = (float)(1.0 / 1.03);
    bool eq = (ratio < HIv) && (ratio > LOv);
    if (eq) {
        float d = a.x - b.x;
        eqs += d * d * cm;
    } else {
        float label = ((ratio >= HIv) ? 1.f : 0.f) + ((ratio <= LOv) ? -1.f : 0.f);
        uns += log1pf(expf((b.x - a.x) * label)) * cm;
    }
}

__global__ void loss_kernel(const float2* __restrict__ pairIT,
                            const float2* __restrict__ anchorC,
                            const int* __restrict__ compV,
                            const int* __restrict__ etot, const int* __restrict__ vtot,
                            const int* __restrict__ ra, const int* __restrict__ rd,
                            const int* __restrict__ rp,
                            float2* __restrict__ partials,
                            unsigned* __restrict__ counter,
                            float* __restrict__ out) {
    int b = blockIdx.x, t = threadIdx.x;
    // XCD-affinity: assuming round-robin block->XCD, image i owns XCDs {2i, 2i+1}
    // -> per-XCD gather working set = one image's 6.3MB pairIT slice (L2+L3 resident).
    // Wrong mapping costs only locality, never correctness.
    int i = (b & 7) >> 1;
    int sub = ((b >> 3) << 1) | (b & 1);          // [0, 512) within image
    int s = sub * 256 + t;
    const float2* pIT = pairIT + (size_t)i * PIX;
    int eT = etot[i], vT = vtot[i];
    int minlen = (eT > 0) ? eT : 1;
    int nval = (vT > 0) ? vT : 1;

    int j = ra[(size_t)i * SNUM + s] % minlen;
    float2 ac = anchorC[(size_t)i * PIX + j];      // one 8B line: pixel + theta
    int anchor = __float_as_int(ac.x);
    float sv = sinf(ac.y), cv = cosf(ac.y);
    int row_a = anchor >> 10, col_a = anchor & (W - 1);

    int pix4[4];
#pragma unroll
    for (int k = 0; k < 4; k++) {
        int r = rd[((size_t)i * 4 + k) * SNUM + s];
        float dist = ((float)r + 2.0f) * ((k < 2) ? -1.f : 1.f);
        int cc = col_a + (int)rintf(dist * cv);    // round-half-even = jnp.round
        int rr = row_a + (int)rintf(dist * sv);
        cc = min(max(cc, 0), W - 1);
        rr = min(max(rr, 0), H - 1);
        pix4[k] = (rr << 10) | cc;
    }
    int2 rr2 = *(const int2*)(rp + (size_t)i * 2 * SNUM + 2 * s);
    int r0 = rr2.x % nval, r1 = rr2.y % nval;
    bool ident = (vT == PIX) || (vT == 0);         // identity compaction cases
    int A = ident ? r0 : compV[(size_t)i * PIX + r0];
    int B = ident ? r1 : compV[(size_t)i * PIX + r1];

    float2 a0 = pIT[pix4[0]], a1 = pIT[pix4[1]], a2 = pIT[pix4[2]], a3 = pIT[pix4[3]];
    float2 b0 = pIT[A], b1 = pIT[B];
    float eqs = 0.f, uns = 0.f;
    pair_term(a0, a1, eqs, uns);
    pair_term(a1, a2, eqs, uns);
    pair_term(a2, a3, eqs, uns);
    pair_term(b0, b1, eqs, uns);

    __shared__ float sEq[256], sUn[256];
    __shared__ int sLast;
    sEq[t] = eqs; sUn[t] = uns;
    __syncthreads();
    for (int o = 128; o > 0; o >>= 1) {
        if (t < o) { sEq[t] += sEq[t + o]; sUn[t] += sUn[t + o]; }
        __syncthreads();
    }
    if (t == 0) {
        partials[b] = make_float2(sEq[0], sUn[0]);
        __threadfence();                           // publish partials device-wide
        unsigned r = atomicAdd(counter, 1u);       // device-scope ticket
        sLast = (r == GRID_L - 1) ? 1 : 0;
    }
    __syncthreads();
    if (sLast) {                                   // last-arriving block reduces
        __threadfence();                           // acquire: see all partials
        double acc = 0.0;
#pragma unroll
        for (int k = 0; k < 8; k++) {
            float2 p = partials[t + k * 256];
            acc += (double)p.x + (double)p.y;
        }
        __shared__ double sDr[256];
        sDr[t] = acc;
        __syncthreads();
        for (int o = 128; o > 0; o >>= 1) {
            if (t < o) sDr[t] += sDr[t + o];
            __syncthreads();
        }
        if (t == 0) {
            double denom = 4.0 * (double)SNUM;     // each mean over 4*S pair terms; ALPHA=1
            out[0] = (float)(sDr[0] / denom / (double)NIMG);
        }
    }
}

extern "C" void kernel_launch(void* const* d_in, const int* in_sizes, int n_in,
                              void* d_out, int out_size, void* d_ws, size_t ws_size,
                              hipStream_t stream) {
    const float* inputs  = (const float*)d_in[0];
    const float* targets = (const float*)d_in[1];
    const float* images  = (const float*)d_in[2];
    const int* ra = (const int*)d_in[3];
    const int* rd = (const int*)d_in[4];
    const int* rp = (const int*)d_in[5];
    float* out = (float*)d_out;

    char* ws = (char*)d_ws;
    float*    thrArr   = (float*)ws;                       // [4]
    int*      etot     = (int*)(ws + 16);                  // [4]
    int*      vtot     = (int*)(ws + 32);                  // [4]
    unsigned* counter  = (unsigned*)(ws + 48);             // ticket (zeroed by K0)
    float*    blockmax = (float*)(ws + 64);                // [12288]
    int*      blkE     = (int*)(ws + 49216);               // [12288]
    int*      blkV     = (int*)(ws + 98368);               // [12288]
    float2*   partials = (float2*)(ws + 147520);           // [2048]
    unsigned long long* vBits = (unsigned long long*)(ws + 196608);   // 393216 B
    unsigned long long* eBits = (unsigned long long*)(ws + 589824);   // 393216 B
    float2*   pairIT   = (float2*)(ws + 1048576);          // 25.2 MB
    float2*   anchorC  = (float2*)(ws + 26214400);         // 25.2 MB (worst case)
    int*      compV    = (int*)(ws + 51380224);            // 12.6 MB
    // total ~61 MB; every word written before read -> no memset needed

    sobel_pack_kernel<<<NB, 256, 0, stream>>>(inputs, targets, images,
                                              pairIT, vBits, blockmax, blkV, counter);
    emax_scanv_kernel<<<NIMG, 1024, 0, stream>>>(blockmax, blkV, thrArr, vtot);
    ebits_kernel<<<NB, 256, 0, stream>>>(images, thrArr, eBits, blkE);
    scane_kernel<<<NIMG, 1024, 0, stream>>>(blkE, etot);
    scatter_kernel<<<NB, 256, 0, stream>>>(images, eBits, vBits, blkE, blkV, vtot,
                                           anchorC, compV);
    loss_kernel<<<GRID_L, 256, 0, stream>>>(pairIT, anchorC, compV,
                                            etot, vtot, ra, rd, rp,
                                            partials, counter, out);
}